// Round 1
// baseline (153.341 us; speedup 1.0000x reference)
//
#include <hip/hip_runtime.h>

#define LOG2PI 1.8378770664093453f

// ---- reduction helpers (block of 128 or 256 threads, wave=64) ----

__device__ __forceinline__ float waveReduceSum(float v) {
#pragma unroll
    for (int o = 32; o > 0; o >>= 1) v += __shfl_down(v, o, 64);
    return v;
}

__device__ __forceinline__ float waveReduceMax(float v) {
#pragma unroll
    for (int o = 32; o > 0; o >>= 1) v = fmaxf(v, __shfl_down(v, o, 64));
    return v;
}

// returns the reduced value to ALL threads
__device__ __forceinline__ float blockReduceSum(float v, float* sh) {
    int lane = threadIdx.x & 63, wid = threadIdx.x >> 6, nw = blockDim.x >> 6;
    v = waveReduceSum(v);
    __syncthreads();               // protect sh reuse across consecutive calls
    if (lane == 0) sh[wid] = v;
    __syncthreads();
    float r = sh[0];
    for (int w = 1; w < nw; ++w) r += sh[w];
    return r;
}

__device__ __forceinline__ float blockReduceMax(float v, float* sh) {
    int lane = threadIdx.x & 63, wid = threadIdx.x >> 6, nw = blockDim.x >> 6;
    v = waveReduceMax(v);
    __syncthreads();
    if (lane == 0) sh[wid] = v;
    __syncthreads();
    float r = sh[0];
    for (int w = 1; w < nw; ++w) r = fmaxf(r, sh[w]);
    return r;
}

// ---- constants: B=128, T=32, DF=256, DZ=128 ----

// grid 4096 = b*32+t, block 128 (=d). ez[b,t,d] = exp(-2*zlv); cz[t*128+b] = sum_d 2*zlv
__global__ void prep_z(const float* __restrict__ zlv, float* __restrict__ ez,
                       float* __restrict__ cz) {
    __shared__ float sh[4];
    int blk = blockIdx.x;
    int b = blk >> 5, t = blk & 31;
    int d = threadIdx.x;
    int idx = b * 4096 + t * 128 + d;
    float lv = zlv[idx];
    ez[idx] = __expf(-2.f * lv) * 0.f + expf(-2.f * lv); // keep precise expf
    float s = blockReduceSum(2.f * lv, sh);
    if (d == 0) cz[t * 128 + b] = s;
}

// grid 128 = b, block 256 (=d). ef[b,d] = exp(-2*flv); cf[b] = sum_d 2*flv
__global__ void prep_f(const float* __restrict__ flv, float* __restrict__ ef,
                       float* __restrict__ cf) {
    __shared__ float sh[4];
    int b = blockIdx.x, d = threadIdx.x;
    int idx = b * 256 + d;
    float lv = flv[idx];
    ef[idx] = expf(-2.f * lv);
    float s = blockReduceSum(2.f * lv, sh);
    if (d == 0) cf[b] = s;
}

// grid 128 = i, block 128 = j. F[i*128+j] = logq_f_sum[i,j]; lse_f[i] = logsumexp_j
__global__ void fker(const float* __restrict__ fm, const float* __restrict__ fs,
                     const float* __restrict__ ef, const float* __restrict__ cf,
                     float* __restrict__ F, float* __restrict__ lse_f) {
    __shared__ float s_fs[256];
    __shared__ float sh[4];
    int i = blockIdx.x, j = threadIdx.x;
    s_fs[j] = fs[i * 256 + j];
    s_fs[j + 128] = fs[i * 256 + 128 + j];
    __syncthreads();
    const float4* fm4 = (const float4*)(fm + j * 256);
    const float4* ef4 = (const float4*)(ef + j * 256);
    float acc = 0.f;
#pragma unroll 8
    for (int d4 = 0; d4 < 64; ++d4) {
        float4 m4 = fm4[d4];
        float4 e4 = ef4[d4];
        float d0 = s_fs[d4 * 4 + 0] - m4.x;
        float d1 = s_fs[d4 * 4 + 1] - m4.y;
        float d2 = s_fs[d4 * 4 + 2] - m4.z;
        float d3 = s_fs[d4 * 4 + 3] - m4.w;
        acc = fmaf(d0 * d0, e4.x, acc);
        acc = fmaf(d1 * d1, e4.y, acc);
        acc = fmaf(d2 * d2, e4.z, acc);
        acc = fmaf(d3 * d3, e4.w, acc);
    }
    float Fij = -0.5f * (acc + cf[j] + 256.f * LOG2PI);
    F[i * 128 + j] = Fij;
    float m = blockReduceMax(Fij, sh);
    float s = blockReduceSum(expf(Fij - m), sh);
    if (j == 0) lse_f[i] = m + logf(s);
}

// grid 4096 = t*128+i, block 128 = j.
__global__ void zker(const float* __restrict__ zm, const float* __restrict__ zs,
                     const float* __restrict__ ez, const float* __restrict__ cz,
                     const float* __restrict__ F, const float* __restrict__ lse_f,
                     const int* __restrict__ num_train, float* __restrict__ val) {
    __shared__ float s_zs[128];
    __shared__ float sh[4];
    int blk = blockIdx.x;
    int t = blk >> 7;
    int i = blk & 127;
    int j = threadIdx.x;
    s_zs[j] = zs[i * 4096 + t * 128 + j];   // z_sample[i, t, :]
    __syncthreads();
    const float4* zm4 = (const float4*)(zm + j * 4096 + t * 128);
    const float4* ez4 = (const float4*)(ez + j * 4096 + t * 128);
    float acc = 0.f;
#pragma unroll 8
    for (int d4 = 0; d4 < 32; ++d4) {
        float4 m4 = zm4[d4];
        float4 e4 = ez4[d4];
        float d0 = s_zs[d4 * 4 + 0] - m4.x;
        float d1 = s_zs[d4 * 4 + 1] - m4.y;
        float d2 = s_zs[d4 * 4 + 2] - m4.z;
        float d3 = s_zs[d4 * 4 + 3] - m4.w;
        acc = fmaf(d0 * d0, e4.x, acc);
        acc = fmaf(d1 * d1, e4.y, acc);
        acc = fmaf(d2 * d2, e4.z, acc);
        acc = fmaf(d3 * d3, e4.w, acc);
    }
    float row_z = -0.5f * (acc + cz[t * 128 + j] + 128.f * LOG2PI);
    float fz = row_z + F[i * 128 + j];

    float mz = blockReduceMax(row_z, sh);
    float sz = blockReduceSum(expf(row_z - mz), sh);
    float mf = blockReduceMax(fz, sh);
    float sf = blockReduceSum(expf(fz - mf), sh);

    if (j == 0) {
        float lse_z = mz + logf(sz);
        float lse_fz = mf + logf(sf);
        float log_norm = logf(128.f * (float)num_train[0]);
        // logq_fz - logq_f - logq_z = lse_fz - lse_f - lse_z + log_norm
        float v = lse_fz - lse_f[i] - lse_z + log_norm;
        val[blk] = v > 0.f ? v : 0.f;
    }
}

// 1 block, 256 threads: mean over 4096 vals
__global__ void rker(const float* __restrict__ val, float* __restrict__ out) {
    __shared__ float sh[4];
    float s = 0.f;
    for (int k = threadIdx.x; k < 4096; k += 256) s += val[k];
    s = blockReduceSum(s, sh);
    if (threadIdx.x == 0) out[0] = s / 4096.f;
}

extern "C" void kernel_launch(void* const* d_in, const int* in_sizes, int n_in,
                              void* d_out, int out_size, void* d_ws, size_t ws_size,
                              hipStream_t stream) {
    const float* f_mean   = (const float*)d_in[0];
    const float* f_logvar = (const float*)d_in[1];
    const float* f_sample = (const float*)d_in[2];
    const float* z_mean   = (const float*)d_in[3];
    const float* z_logvar = (const float*)d_in[4];
    const float* z_sample = (const float*)d_in[5];
    const int*   num_train = (const int*)d_in[6];
    float* out = (float*)d_out;

    float* ws    = (float*)d_ws;
    float* ez    = ws;               // 524288  exp(-2*z_logvar), [b,t,d] layout
    float* cz    = ez + 524288;      // 4096    sum_d 2*z_logvar, [t*128+b]
    float* ef    = cz + 4096;        // 32768   exp(-2*f_logvar)
    float* cf    = ef + 32768;       // 128     sum_d 2*f_logvar
    float* F     = cf + 128;         // 16384   logq_f_sum[i*128+j]
    float* lse_f = F + 16384;        // 128
    float* val   = lse_f + 128;      // 4096    relu terms per (t,i)

    prep_z<<<4096, 128, 0, stream>>>(z_logvar, ez, cz);
    prep_f<<<128, 256, 0, stream>>>(f_logvar, ef, cf);
    fker<<<128, 128, 0, stream>>>(f_mean, f_sample, ef, cf, F, lse_f);
    zker<<<4096, 128, 0, stream>>>(z_mean, z_sample, ez, cz, F, lse_f, num_train, val);
    rker<<<1, 256, 0, stream>>>(val, out);
}

// Round 2
// 106.471 us; speedup vs baseline: 1.4402x; 1.4402x over previous
//
#include <hip/hip_runtime.h>

#define LOG2PI 1.8378770664093453f

// Shapes: B=128, T=32, DF=256, DZ=128

// ---- reduction helpers ----

__device__ __forceinline__ float waveReduceSum(float v) {
#pragma unroll
    for (int o = 32; o > 0; o >>= 1) v += __shfl_down(v, o, 64);
    return v;
}

__device__ __forceinline__ float waveReduceMax(float v) {
#pragma unroll
    for (int o = 32; o > 0; o >>= 1) v = fmaxf(v, __shfl_down(v, o, 64));
    return v;
}

// block of nw waves; returns reduced value to ALL threads
__device__ __forceinline__ float blockReduceSum(float v, float* sh) {
    int lane = threadIdx.x & 63, wid = threadIdx.x >> 6, nw = blockDim.x >> 6;
    v = waveReduceSum(v);
    __syncthreads();
    if (lane == 0) sh[wid] = v;
    __syncthreads();
    float r = sh[0];
    for (int w = 1; w < nw; ++w) r += sh[w];
    return r;
}

__device__ __forceinline__ float blockReduceMax(float v, float* sh) {
    int lane = threadIdx.x & 63, wid = threadIdx.x >> 6, nw = blockDim.x >> 6;
    v = waveReduceMax(v);
    __syncthreads();
    if (lane == 0) sh[wid] = v;
    __syncthreads();
    float r = sh[0];
    for (int w = 1; w < nw; ++w) r = fmaxf(r, sh[w]);
    return r;
}

// float4 variants for a 2-wave (128-thread) block
__device__ __forceinline__ float4 blockMax4(float4 v, float4* sh) {
#pragma unroll
    for (int o = 32; o > 0; o >>= 1) {
        v.x = fmaxf(v.x, __shfl_down(v.x, o, 64));
        v.y = fmaxf(v.y, __shfl_down(v.y, o, 64));
        v.z = fmaxf(v.z, __shfl_down(v.z, o, 64));
        v.w = fmaxf(v.w, __shfl_down(v.w, o, 64));
    }
    int lane = threadIdx.x & 63, wid = threadIdx.x >> 6;
    __syncthreads();
    if (lane == 0) sh[wid] = v;
    __syncthreads();
    float4 a = sh[0], b = sh[1];
    return make_float4(fmaxf(a.x, b.x), fmaxf(a.y, b.y),
                       fmaxf(a.z, b.z), fmaxf(a.w, b.w));
}

__device__ __forceinline__ float4 blockSum4(float4 v, float4* sh) {
#pragma unroll
    for (int o = 32; o > 0; o >>= 1) {
        v.x += __shfl_down(v.x, o, 64);
        v.y += __shfl_down(v.y, o, 64);
        v.z += __shfl_down(v.z, o, 64);
        v.w += __shfl_down(v.w, o, 64);
    }
    int lane = threadIdx.x & 63, wid = threadIdx.x >> 6;
    __syncthreads();
    if (lane == 0) sh[wid] = v;
    __syncthreads();
    float4 a = sh[0], b = sh[1];
    return make_float4(a.x + b.x, a.y + b.y, a.z + b.z, a.w + b.w);
}

// ---- transpose+exp for z: zme[(t*128+d)*128 + b] = {zm[b,t,d], exp(-2*zlv[b,t,d])}
// grid 512 = t(32) x bt(4) x dt(4), block 256
__global__ void tz_ker(const float* __restrict__ zm, const float* __restrict__ zlv,
                       float2* __restrict__ zme) {
    __shared__ float sm[32][33];
    __shared__ float se[32][33];
    int blk = blockIdx.x;
    int t = blk >> 4;
    int bt = (blk >> 2) & 3;
    int dt = blk & 3;
    int tx = threadIdx.x & 31;   // d_local on load, b_local on store
    int ty = threadIdx.x >> 5;   // 0..7
    int b0 = bt * 32, d0 = dt * 32;
#pragma unroll
    for (int k = 0; k < 4; ++k) {
        int bl = ty + k * 8;
        int idx = (b0 + bl) * 4096 + t * 128 + d0 + tx;   // coalesced in d
        sm[bl][tx] = zm[idx];
        se[bl][tx] = expf(-2.f * zlv[idx]);
    }
    __syncthreads();
#pragma unroll
    for (int k = 0; k < 4; ++k) {
        int dl = ty + k * 8;
        zme[(t * 128 + d0 + dl) * 128 + b0 + tx] =
            make_float2(sm[tx][dl], se[tx][dl]);          // coalesced in b
    }
}

// ---- transpose+exp for f: fme[d*128 + b] = {fm[b,d], exp(-2*flv[b,d])}
// grid 32 = bt(4) x dt(8), block 256
__global__ void tf_ker(const float* __restrict__ fm, const float* __restrict__ flv,
                       float2* __restrict__ fme) {
    __shared__ float sm[32][33];
    __shared__ float se[32][33];
    int blk = blockIdx.x;
    int bt = blk >> 3;
    int dt = blk & 7;
    int tx = threadIdx.x & 31;
    int ty = threadIdx.x >> 5;
    int b0 = bt * 32, d0 = dt * 32;
#pragma unroll
    for (int k = 0; k < 4; ++k) {
        int bl = ty + k * 8;
        int idx = (b0 + bl) * 256 + d0 + tx;
        sm[bl][tx] = fm[idx];
        se[bl][tx] = expf(-2.f * flv[idx]);
    }
    __syncthreads();
#pragma unroll
    for (int k = 0; k < 4; ++k) {
        int dl = ty + k * 8;
        fme[(d0 + dl) * 128 + b0 + tx] = make_float2(sm[tx][dl], se[tx][dl]);
    }
}

// ---- per-row logvar sums: cz[t*128+b] = sum_d 2*zlv[b,t,:]; cf[b] = sum_d 2*flv[b,:]
// grid 4224, block 128
__global__ void sums_ker(const float* __restrict__ zlv, const float* __restrict__ flv,
                         float* __restrict__ cz, float* __restrict__ cf) {
    __shared__ float sh[2];
    int blk = blockIdx.x, tid = threadIdx.x;
    if (blk < 4096) {
        int b = blk >> 5, t = blk & 31;
        float s = 2.f * zlv[b * 4096 + t * 128 + tid];
        s = blockReduceSum(s, sh);
        if (tid == 0) cz[t * 128 + b] = s;
    } else {
        int b = blk - 4096;
        float s = 2.f * (flv[b * 256 + tid] + flv[b * 256 + 128 + tid]);
        s = blockReduceSum(s, sh);
        if (tid == 0) cf[b] = s;
    }
}

// ---- F[i,j] + lse_f[i]: grid 128 (i), block 128 (j)
__global__ void fker(const float* __restrict__ fs, const float2* __restrict__ fme,
                     const float* __restrict__ cf,
                     float* __restrict__ F, float* __restrict__ lse_f) {
    __shared__ float s_fs[256];
    __shared__ float sh[2];
    int i = blockIdx.x, j = threadIdx.x;
    s_fs[j] = fs[i * 256 + j];
    s_fs[j + 128] = fs[i * 256 + 128 + j];
    __syncthreads();
    float acc = 0.f;
#pragma unroll 8
    for (int d = 0; d < 256; ++d) {
        float2 me = fme[d * 128 + j];     // coalesced
        float df = s_fs[d] - me.x;        // LDS broadcast
        acc = fmaf(df * df, me.y, acc);
    }
    float Fij = -0.5f * (acc + cf[j] + 256.f * LOG2PI);
    F[i * 128 + j] = Fij;
    float m = blockReduceMax(Fij, sh);
    float s = blockReduceSum(expf(Fij - m), sh);
    if (j == 0) lse_f[i] = m + logf(s);
}

// ---- hot kernel: grid 1024 = t(32) x itile(32), block 128 (j), 4 sample rows per block
__global__ void zker(const float* __restrict__ zs, const float2* __restrict__ zme,
                     const float* __restrict__ cz, const float* __restrict__ F,
                     const float* __restrict__ lse_f, const int* __restrict__ num_train,
                     float* __restrict__ val) {
    __shared__ float4 s_zs[128];   // s_zs[d] = {zs[i0+0][d], .., zs[i0+3][d]} for this t
    __shared__ float4 sh4[2];
    int blk = blockIdx.x;
    int t = blk >> 5;
    int i0 = (blk & 31) * 4;
    int j = threadIdx.x;

    float* s_zs_f = (float*)s_zs;
#pragma unroll
    for (int k = 0; k < 4; ++k)
        s_zs_f[j * 4 + k] = zs[(i0 + k) * 4096 + t * 128 + j];  // coalesced reads
    __syncthreads();

    const float2* zmt = zme + t * 16384;
    float4 acc = make_float4(0.f, 0.f, 0.f, 0.f);
#pragma unroll 8
    for (int d = 0; d < 128; ++d) {
        float2 me = zmt[d * 128 + j];   // coalesced 8B/lane
        float4 z = s_zs[d];             // LDS broadcast (ds_read_b128, same addr)
        float d0 = z.x - me.x; acc.x = fmaf(d0 * d0, me.y, acc.x);
        float d1 = z.y - me.x; acc.y = fmaf(d1 * d1, me.y, acc.y);
        float d2 = z.z - me.x; acc.z = fmaf(d2 * d2, me.y, acc.z);
        float d3 = z.w - me.x; acc.w = fmaf(d3 * d3, me.y, acc.w);
    }

    float base = -0.5f * (cz[t * 128 + j] + 128.f * LOG2PI);
    float4 rz = make_float4(-0.5f * acc.x + base, -0.5f * acc.y + base,
                            -0.5f * acc.z + base, -0.5f * acc.w + base);
    float4 fz = make_float4(rz.x + F[(i0 + 0) * 128 + j],
                            rz.y + F[(i0 + 1) * 128 + j],
                            rz.z + F[(i0 + 2) * 128 + j],
                            rz.w + F[(i0 + 3) * 128 + j]);

    float4 mz = blockMax4(rz, sh4);
    float4 e = make_float4(expf(rz.x - mz.x), expf(rz.y - mz.y),
                           expf(rz.z - mz.z), expf(rz.w - mz.w));
    float4 sz = blockSum4(e, sh4);
    float4 mf = blockMax4(fz, sh4);
    e = make_float4(expf(fz.x - mf.x), expf(fz.y - mf.y),
                    expf(fz.z - mf.z), expf(fz.w - mf.w));
    float4 sf = blockSum4(e, sh4);

    if (j == 0) {
        float log_norm = logf(128.f * (float)num_train[0]);
        float lz[4] = {mz.x + logf(sz.x), mz.y + logf(sz.y),
                       mz.z + logf(sz.z), mz.w + logf(sz.w)};
        float lfz[4] = {mf.x + logf(sf.x), mf.y + logf(sf.y),
                        mf.z + logf(sf.z), mf.w + logf(sf.w)};
#pragma unroll
        for (int k = 0; k < 4; ++k) {
            float v = lfz[k] - lse_f[i0 + k] - lz[k] + log_norm;
            val[t * 128 + i0 + k] = v > 0.f ? v : 0.f;
        }
    }
}

// ---- final mean: 1 block, 256 threads
__global__ void rker(const float* __restrict__ val, float* __restrict__ out) {
    __shared__ float sh[4];
    float s = 0.f;
    for (int k = threadIdx.x; k < 4096; k += 256) s += val[k];
    s = blockReduceSum(s, sh);
    if (threadIdx.x == 0) out[0] = s / 4096.f;
}

extern "C" void kernel_launch(void* const* d_in, const int* in_sizes, int n_in,
                              void* d_out, int out_size, void* d_ws, size_t ws_size,
                              hipStream_t stream) {
    const float* f_mean    = (const float*)d_in[0];
    const float* f_logvar  = (const float*)d_in[1];
    const float* f_sample  = (const float*)d_in[2];
    const float* z_mean    = (const float*)d_in[3];
    const float* z_logvar  = (const float*)d_in[4];
    const float* z_sample  = (const float*)d_in[5];
    const int*   num_train = (const int*)d_in[6];
    float* out = (float*)d_out;

    float* ws    = (float*)d_ws;
    float2* zme  = (float2*)ws;            // 524288 float2 (4 MB)
    float2* fme  = (float2*)(ws + 1048576);// 32768 float2 (256 KB)
    float*  cz   = ws + 1048576 + 65536;   // 4096
    float*  cf   = cz + 4096;              // 128
    float*  F    = cf + 128;               // 16384
    float*  lse_f= F + 16384;              // 128
    float*  val  = lse_f + 128;            // 4096

    tz_ker<<<512, 256, 0, stream>>>(z_mean, z_logvar, zme);
    tf_ker<<<32, 256, 0, stream>>>(f_mean, f_logvar, fme);
    sums_ker<<<4224, 128, 0, stream>>>(z_logvar, f_logvar, cz, cf);
    fker<<<128, 128, 0, stream>>>(f_sample, fme, cf, F, lse_f);
    zker<<<1024, 128, 0, stream>>>(z_sample, zme, cz, F, lse_f, num_train, val);
    rker<<<1, 256, 0, stream>>>(val, out);
}

// Round 3
// 105.582 us; speedup vs baseline: 1.4523x; 1.0084x over previous
//
#include <hip/hip_runtime.h>

#define LOG2PI 1.8378770664093453f

// Shapes: B=128, T=32, DF=256, DZ=128

// ---- reduction helpers ----

__device__ __forceinline__ float waveReduceSum(float v) {
#pragma unroll
    for (int o = 32; o > 0; o >>= 1) v += __shfl_down(v, o, 64);
    return v;
}

__device__ __forceinline__ float waveReduceMax(float v) {
#pragma unroll
    for (int o = 32; o > 0; o >>= 1) v = fmaxf(v, __shfl_down(v, o, 64));
    return v;
}

// block reduce, returns value to ALL threads; sh must hold blockDim/64 floats
__device__ __forceinline__ float blockReduceSum(float v, float* sh) {
    int lane = threadIdx.x & 63, wid = threadIdx.x >> 6, nw = blockDim.x >> 6;
    v = waveReduceSum(v);
    __syncthreads();
    if (lane == 0) sh[wid] = v;
    __syncthreads();
    float r = sh[0];
    for (int w = 1; w < nw; ++w) r += sh[w];
    return r;
}

__device__ __forceinline__ float blockReduceMax(float v, float* sh) {
    int lane = threadIdx.x & 63, wid = threadIdx.x >> 6, nw = blockDim.x >> 6;
    v = waveReduceMax(v);
    __syncthreads();
    if (lane == 0) sh[wid] = v;
    __syncthreads();
    float r = sh[0];
    for (int w = 1; w < nw; ++w) r = fmaxf(r, sh[w]);
    return r;
}

// float4 variants for a 2-wave (128-thread) block
__device__ __forceinline__ float4 blockMax4(float4 v, float4* sh) {
#pragma unroll
    for (int o = 32; o > 0; o >>= 1) {
        v.x = fmaxf(v.x, __shfl_down(v.x, o, 64));
        v.y = fmaxf(v.y, __shfl_down(v.y, o, 64));
        v.z = fmaxf(v.z, __shfl_down(v.z, o, 64));
        v.w = fmaxf(v.w, __shfl_down(v.w, o, 64));
    }
    int lane = threadIdx.x & 63, wid = threadIdx.x >> 6;
    __syncthreads();
    if (lane == 0) sh[wid] = v;
    __syncthreads();
    float4 a = sh[0], b = sh[1];
    return make_float4(fmaxf(a.x, b.x), fmaxf(a.y, b.y),
                       fmaxf(a.z, b.z), fmaxf(a.w, b.w));
}

__device__ __forceinline__ float4 blockSum4(float4 v, float4* sh) {
#pragma unroll
    for (int o = 32; o > 0; o >>= 1) {
        v.x += __shfl_down(v.x, o, 64);
        v.y += __shfl_down(v.y, o, 64);
        v.z += __shfl_down(v.z, o, 64);
        v.w += __shfl_down(v.w, o, 64);
    }
    int lane = threadIdx.x & 63, wid = threadIdx.x >> 6;
    __syncthreads();
    if (lane == 0) sh[wid] = v;
    __syncthreads();
    float4 a = sh[0], b = sh[1];
    return make_float4(a.x + b.x, a.y + b.y, a.z + b.z, a.w + b.w);
}

// ---- fused prep: grid 2721 blocks x 256 threads
//  [0,512)        tz: zme[(t*128+d)*128+b] = {zm[b,t,d], exp(-2*zlv[b,t,d])}
//  [512,544)      tf: fme[d*128+b]        = {fm[b,d],   exp(-2*flv[b,d])}
//  [544,2592)     z row sums: cz[t*128+b] = sum_d 2*zlv[b,t,d]   (2 rows/block)
//  [2592,2720)    f row sums: cf[b]       = sum_d 2*flv[b,d]
//  [2720]         zero out[0]
#define NB_TZ 512
#define NB_TF 32
#define NB_ZS 2048
#define NB_FS 128

__global__ void prep(const float* __restrict__ zm, const float* __restrict__ zlv,
                     const float* __restrict__ fm, const float* __restrict__ flv,
                     float2* __restrict__ zme, float2* __restrict__ fme,
                     float* __restrict__ cz, float* __restrict__ cf,
                     float* __restrict__ out) {
    __shared__ float S[2 * 32 * 33];   // 8448 B, reused per branch
    float (*sm)[33] = (float(*)[33])S;
    float (*se)[33] = (float(*)[33])(S + 32 * 33);
    int blk = blockIdx.x;
    int tid = threadIdx.x;

    if (blk < NB_TZ) {
        // transpose+exp z: blk = t(32) x bt(4) x dt(4)
        int t = blk >> 4, bt = (blk >> 2) & 3, dt = blk & 3;
        int tx = tid & 31, ty = tid >> 5;
        int b0 = bt * 32, d0 = dt * 32;
#pragma unroll
        for (int k = 0; k < 4; ++k) {
            int bl = ty + k * 8;
            int idx = (b0 + bl) * 4096 + t * 128 + d0 + tx;   // coalesced in d
            sm[bl][tx] = zm[idx];
            se[bl][tx] = expf(-2.f * zlv[idx]);
        }
        __syncthreads();
#pragma unroll
        for (int k = 0; k < 4; ++k) {
            int dl = ty + k * 8;
            zme[(t * 128 + d0 + dl) * 128 + b0 + tx] =
                make_float2(sm[tx][dl], se[tx][dl]);          // coalesced in b
        }
    } else if (blk < NB_TZ + NB_TF) {
        // transpose+exp f: blk-512 = bt(4) x dt(8)
        int r = blk - NB_TZ;
        int bt = r >> 3, dt = r & 7;
        int tx = tid & 31, ty = tid >> 5;
        int b0 = bt * 32, d0 = dt * 32;
#pragma unroll
        for (int k = 0; k < 4; ++k) {
            int bl = ty + k * 8;
            int idx = (b0 + bl) * 256 + d0 + tx;
            sm[bl][tx] = fm[idx];
            se[bl][tx] = expf(-2.f * flv[idx]);
        }
        __syncthreads();
#pragma unroll
        for (int k = 0; k < 4; ++k) {
            int dl = ty + k * 8;
            fme[(d0 + dl) * 128 + b0 + tx] = make_float2(sm[tx][dl], se[tx][dl]);
        }
    } else if (blk < NB_TZ + NB_TF + NB_ZS) {
        // z row sums, 2 rows per block; row r: b=r>>5, t=r&31
        int r0 = (blk - NB_TZ - NB_TF) * 2;
        int half = tid >> 7, lane = tid & 127;
        int r = r0 + half;
        int b = r >> 5, t = r & 31;
        float v = 2.f * zlv[b * 4096 + t * 128 + lane];
        v = waveReduceSum(v);
        int wid = tid >> 6;
        if ((tid & 63) == 0) S[wid] = v;
        __syncthreads();
        if (tid == 0)   cz[(r0 & 31) * 128 + (r0 >> 5)] = S[0] + S[1];
        if (tid == 128) { int r1 = r0 + 1; cz[(r1 & 31) * 128 + (r1 >> 5)] = S[2] + S[3]; }
    } else if (blk < NB_TZ + NB_TF + NB_ZS + NB_FS) {
        int b = blk - NB_TZ - NB_TF - NB_ZS;
        float v = 2.f * flv[b * 256 + tid];
        v = blockReduceSum(v, S);
        if (tid == 0) cf[b] = v;
    } else {
        if (tid == 0) out[0] = 0.f;
    }
}

// ---- F[i,j] + lse_f[i]: grid 128 (i), block 256 = j(128) x dhalf(2)
__global__ void fker(const float* __restrict__ fs, const float2* __restrict__ fme,
                     const float* __restrict__ cf,
                     float* __restrict__ F, float* __restrict__ lse_f) {
    __shared__ float s_fs[256];
    __shared__ float part[256];
    __shared__ float sh[4];
    int i = blockIdx.x, tid = threadIdx.x;
    int j = tid & 127, dh = tid >> 7;
    s_fs[tid] = fs[i * 256 + tid];
    __syncthreads();
    const float2* fp = fme + dh * 128 * 128;
    const float* ss = s_fs + dh * 128;
    float acc = 0.f;
#pragma unroll 8
    for (int d = 0; d < 128; ++d) {
        float2 me = fp[d * 128 + j];      // coalesced
        float df = ss[d] - me.x;          // LDS broadcast
        acc = fmaf(df * df, me.y, acc);
    }
    part[tid] = acc;
    __syncthreads();
    float Fij = 0.f;
    if (dh == 0) {
        Fij = -0.5f * (acc + part[tid + 128] + cf[j] + 256.f * LOG2PI);
        F[i * 128 + j] = Fij;
    }
    float v = (dh == 0) ? Fij : -INFINITY;
    float m = blockReduceMax(v, sh);
    float e = (dh == 0) ? expf(Fij - m) : 0.f;
    float s = blockReduceSum(e, sh);
    if (tid == 0) lse_f[i] = m + logf(s);
}

// ---- hot kernel + fused mean: grid 1024 = t(32) x itile(32), block 128 (j)
__global__ void zker(const float* __restrict__ zs, const float2* __restrict__ zme,
                     const float* __restrict__ cz, const float* __restrict__ F,
                     const float* __restrict__ lse_f, const int* __restrict__ num_train,
                     float* __restrict__ out) {
    __shared__ float4 s_zs[128];   // s_zs[d] = {zs[i0+0][d], .., zs[i0+3][d]} for this t
    __shared__ float4 sh4[2];
    int blk = blockIdx.x;
    int t = blk >> 5;
    int i0 = (blk & 31) * 4;
    int j = threadIdx.x;

    float* s_zs_f = (float*)s_zs;
#pragma unroll
    for (int k = 0; k < 4; ++k)
        s_zs_f[j * 4 + k] = zs[(i0 + k) * 4096 + t * 128 + j];  // coalesced reads
    __syncthreads();

    const float2* zmt = zme + t * 16384;
    float4 acc = make_float4(0.f, 0.f, 0.f, 0.f);
#pragma unroll 8
    for (int d = 0; d < 128; ++d) {
        float2 me = zmt[d * 128 + j];   // coalesced 8B/lane
        float4 z = s_zs[d];             // LDS same-address broadcast
        float d0 = z.x - me.x; acc.x = fmaf(d0 * d0, me.y, acc.x);
        float d1 = z.y - me.x; acc.y = fmaf(d1 * d1, me.y, acc.y);
        float d2 = z.z - me.x; acc.z = fmaf(d2 * d2, me.y, acc.z);
        float d3 = z.w - me.x; acc.w = fmaf(d3 * d3, me.y, acc.w);
    }

    float base = -0.5f * (cz[t * 128 + j] + 128.f * LOG2PI);
    float4 rz = make_float4(-0.5f * acc.x + base, -0.5f * acc.y + base,
                            -0.5f * acc.z + base, -0.5f * acc.w + base);
    float4 fz = make_float4(rz.x + F[(i0 + 0) * 128 + j],
                            rz.y + F[(i0 + 1) * 128 + j],
                            rz.z + F[(i0 + 2) * 128 + j],
                            rz.w + F[(i0 + 3) * 128 + j]);

    float4 mz = blockMax4(rz, sh4);
    float4 e = make_float4(expf(rz.x - mz.x), expf(rz.y - mz.y),
                           expf(rz.z - mz.z), expf(rz.w - mz.w));
    float4 sz = blockSum4(e, sh4);
    float4 mf = blockMax4(fz, sh4);
    e = make_float4(expf(fz.x - mf.x), expf(fz.y - mf.y),
                    expf(fz.z - mf.z), expf(fz.w - mf.w));
    float4 sf = blockSum4(e, sh4);

    if (j == 0) {
        float log_norm = logf(128.f * (float)num_train[0]);
        float lz[4] = {mz.x + logf(sz.x), mz.y + logf(sz.y),
                       mz.z + logf(sz.z), mz.w + logf(sz.w)};
        float lfz[4] = {mf.x + logf(sf.x), mf.y + logf(sf.y),
                        mf.z + logf(sf.z), mf.w + logf(sf.w)};
        float s = 0.f;
#pragma unroll
        for (int k = 0; k < 4; ++k) {
            float v = lfz[k] - lse_f[i0 + k] - lz[k] + log_norm;
            s += (v > 0.f ? v : 0.f);
        }
        atomicAdd(out, s * (1.f / 4096.f));
    }
}

extern "C" void kernel_launch(void* const* d_in, const int* in_sizes, int n_in,
                              void* d_out, int out_size, void* d_ws, size_t ws_size,
                              hipStream_t stream) {
    const float* f_mean    = (const float*)d_in[0];
    const float* f_logvar  = (const float*)d_in[1];
    const float* f_sample  = (const float*)d_in[2];
    const float* z_mean    = (const float*)d_in[3];
    const float* z_logvar  = (const float*)d_in[4];
    const float* z_sample  = (const float*)d_in[5];
    const int*   num_train = (const int*)d_in[6];
    float* out = (float*)d_out;

    float* ws    = (float*)d_ws;
    float2* zme  = (float2*)ws;              // 524288 float2 (4 MB)
    float2* fme  = (float2*)(ws + 1048576);  // 32768 float2 (256 KB)
    float*  cz   = ws + 1048576 + 65536;     // 4096
    float*  cf   = cz + 4096;                // 128
    float*  F    = cf + 128;                 // 16384
    float*  lse_f= F + 16384;                // 128

    prep<<<NB_TZ + NB_TF + NB_ZS + NB_FS + 1, 256, 0, stream>>>(
        z_mean, z_logvar, f_mean, f_logvar, zme, fme, cz, cf, out);
    fker<<<128, 256, 0, stream>>>(f_sample, fme, cf, F, lse_f);
    zker<<<1024, 128, 0, stream>>>(z_sample, zme, cz, F, lse_f, num_train, out);
}

// Round 4
// 105.199 us; speedup vs baseline: 1.4576x; 1.0036x over previous
//
#include <hip/hip_runtime.h>

#define LOG2PI 1.8378770664093453f

// Shapes: B=128, T=32, DF=256, DZ=128

// ---- reduction helpers ----

__device__ __forceinline__ float waveReduceSum(float v) {
#pragma unroll
    for (int o = 32; o > 0; o >>= 1) v += __shfl_down(v, o, 64);
    return v;
}

__device__ __forceinline__ float waveReduceMax(float v) {
#pragma unroll
    for (int o = 32; o > 0; o >>= 1) v = fmaxf(v, __shfl_down(v, o, 64));
    return v;
}

// block reduce, returns value to ALL threads; sh must hold blockDim/64 floats
__device__ __forceinline__ float blockReduceSum(float v, float* sh) {
    int lane = threadIdx.x & 63, wid = threadIdx.x >> 6, nw = blockDim.x >> 6;
    v = waveReduceSum(v);
    __syncthreads();
    if (lane == 0) sh[wid] = v;
    __syncthreads();
    float r = sh[0];
    for (int w = 1; w < nw; ++w) r += sh[w];
    return r;
}

__device__ __forceinline__ float blockReduceMax(float v, float* sh) {
    int lane = threadIdx.x & 63, wid = threadIdx.x >> 6, nw = blockDim.x >> 6;
    v = waveReduceMax(v);
    __syncthreads();
    if (lane == 0) sh[wid] = v;
    __syncthreads();
    float r = sh[0];
    for (int w = 1; w < nw; ++w) r = fmaxf(r, sh[w]);
    return r;
}

// ---- per-HALF float4 reductions for a 256-thread block (halves = waves {0,1} / {2,3}).
// Each half reduces over its own 128 lanes; result broadcast to all lanes of that half.
__device__ __forceinline__ float4 halfMax4(float4 v, float4* sh) {
#pragma unroll
    for (int o = 32; o > 0; o >>= 1) {
        v.x = fmaxf(v.x, __shfl_down(v.x, o, 64));
        v.y = fmaxf(v.y, __shfl_down(v.y, o, 64));
        v.z = fmaxf(v.z, __shfl_down(v.z, o, 64));
        v.w = fmaxf(v.w, __shfl_down(v.w, o, 64));
    }
    int wid = threadIdx.x >> 6;
    __syncthreads();                       // protect sh reuse
    if ((threadIdx.x & 63) == 0) sh[wid] = v;
    __syncthreads();
    int hb = (threadIdx.x >> 7) << 1;      // 0 or 2
    float4 a = sh[hb], b = sh[hb + 1];
    return make_float4(fmaxf(a.x, b.x), fmaxf(a.y, b.y),
                       fmaxf(a.z, b.z), fmaxf(a.w, b.w));
}

__device__ __forceinline__ float4 halfSum4(float4 v, float4* sh) {
#pragma unroll
    for (int o = 32; o > 0; o >>= 1) {
        v.x += __shfl_down(v.x, o, 64);
        v.y += __shfl_down(v.y, o, 64);
        v.z += __shfl_down(v.z, o, 64);
        v.w += __shfl_down(v.w, o, 64);
    }
    int wid = threadIdx.x >> 6;
    __syncthreads();
    if ((threadIdx.x & 63) == 0) sh[wid] = v;
    __syncthreads();
    int hb = (threadIdx.x >> 7) << 1;
    float4 a = sh[hb], b = sh[hb + 1];
    return make_float4(a.x + b.x, a.y + b.y, a.z + b.z, a.w + b.w);
}

// ---- fused prep: grid 2721 blocks x 256 threads
#define NB_TZ 512
#define NB_TF 32
#define NB_ZS 2048
#define NB_FS 128

__global__ void prep(const float* __restrict__ zm, const float* __restrict__ zlv,
                     const float* __restrict__ fm, const float* __restrict__ flv,
                     float2* __restrict__ zme, float2* __restrict__ fme,
                     float* __restrict__ cz, float* __restrict__ cf,
                     float* __restrict__ out) {
    __shared__ float S[2 * 32 * 33];   // 8448 B, reused per branch
    float (*sm)[33] = (float(*)[33])S;
    float (*se)[33] = (float(*)[33])(S + 32 * 33);
    int blk = blockIdx.x;
    int tid = threadIdx.x;

    if (blk < NB_TZ) {
        // transpose+exp z: blk = t(32) x bt(4) x dt(4)
        int t = blk >> 4, bt = (blk >> 2) & 3, dt = blk & 3;
        int tx = tid & 31, ty = tid >> 5;
        int b0 = bt * 32, d0 = dt * 32;
#pragma unroll
        for (int k = 0; k < 4; ++k) {
            int bl = ty + k * 8;
            int idx = (b0 + bl) * 4096 + t * 128 + d0 + tx;   // coalesced in d
            sm[bl][tx] = zm[idx];
            se[bl][tx] = expf(-2.f * zlv[idx]);
        }
        __syncthreads();
#pragma unroll
        for (int k = 0; k < 4; ++k) {
            int dl = ty + k * 8;
            zme[(t * 128 + d0 + dl) * 128 + b0 + tx] =
                make_float2(sm[tx][dl], se[tx][dl]);          // coalesced in b
        }
    } else if (blk < NB_TZ + NB_TF) {
        // transpose+exp f: blk-512 = bt(4) x dt(8)
        int r = blk - NB_TZ;
        int bt = r >> 3, dt = r & 7;
        int tx = tid & 31, ty = tid >> 5;
        int b0 = bt * 32, d0 = dt * 32;
#pragma unroll
        for (int k = 0; k < 4; ++k) {
            int bl = ty + k * 8;
            int idx = (b0 + bl) * 256 + d0 + tx;
            sm[bl][tx] = fm[idx];
            se[bl][tx] = expf(-2.f * flv[idx]);
        }
        __syncthreads();
#pragma unroll
        for (int k = 0; k < 4; ++k) {
            int dl = ty + k * 8;
            fme[(d0 + dl) * 128 + b0 + tx] = make_float2(sm[tx][dl], se[tx][dl]);
        }
    } else if (blk < NB_TZ + NB_TF + NB_ZS) {
        // z row sums, 2 rows per block; row r: b=r>>5, t=r&31
        int r0 = (blk - NB_TZ - NB_TF) * 2;
        int half = tid >> 7, lane = tid & 127;
        int r = r0 + half;
        int b = r >> 5, t = r & 31;
        float v = 2.f * zlv[b * 4096 + t * 128 + lane];
        v = waveReduceSum(v);
        int wid = tid >> 6;
        if ((tid & 63) == 0) S[wid] = v;
        __syncthreads();
        if (tid == 0)   cz[(r0 & 31) * 128 + (r0 >> 5)] = S[0] + S[1];
        if (tid == 128) { int r1 = r0 + 1; cz[(r1 & 31) * 128 + (r1 >> 5)] = S[2] + S[3]; }
    } else if (blk < NB_TZ + NB_TF + NB_ZS + NB_FS) {
        int b = blk - NB_TZ - NB_TF - NB_ZS;
        float v = 2.f * flv[b * 256 + tid];
        v = blockReduceSum(v, S);
        if (tid == 0) cf[b] = v;
    } else {
        if (tid == 0) out[0] = 0.f;
    }
}

// ---- F[i,j] + lse_f[i]: grid 128 (i), block 256 = j(128) x dhalf(2)
__global__ void fker(const float* __restrict__ fs, const float2* __restrict__ fme,
                     const float* __restrict__ cf,
                     float* __restrict__ F, float* __restrict__ lse_f) {
    __shared__ float s_fs[256];
    __shared__ float part[256];
    __shared__ float sh[4];
    int i = blockIdx.x, tid = threadIdx.x;
    int j = tid & 127, dh = tid >> 7;
    s_fs[tid] = fs[i * 256 + tid];
    __syncthreads();
    const float2* fp = fme + dh * 128 * 128;
    const float* ss = s_fs + dh * 128;
    float acc = 0.f;
#pragma unroll 8
    for (int d = 0; d < 128; ++d) {
        float2 me = fp[d * 128 + j];      // coalesced
        float df = ss[d] - me.x;          // LDS broadcast
        acc = fmaf(df * df, me.y, acc);
    }
    part[tid] = acc;
    __syncthreads();
    float Fij = 0.f;
    if (dh == 0) {
        Fij = -0.5f * (acc + part[tid + 128] + cf[j] + 256.f * LOG2PI);
        F[i * 128 + j] = Fij;
    }
    float v = (dh == 0) ? Fij : -INFINITY;
    float m = blockReduceMax(v, sh);
    float e = (dh == 0) ? expf(Fij - m) : 0.f;
    float s = blockReduceSum(e, sh);
    if (tid == 0) lse_f[i] = m + logf(s);
}

// ---- hot kernel + fused mean: grid 512 blocks x 256 threads.
// Block b -> t = (b&7) + 8*(b>>7)  [XCD-affine: all 16 blocks of a t share b%8],
//            i0 = ((b>>3)&15)*8   [i-tile of 8].
// Threads: j = tid&127 (mean-batch index), h = tid>>7 (d-half: h*64..h*64+63).
__global__ void zker(const float* __restrict__ zs, const float2* __restrict__ zme,
                     const float* __restrict__ cz, const float* __restrict__ F,
                     const float* __restrict__ lse_f, const int* __restrict__ num_train,
                     float* __restrict__ out) {
    __shared__ float s_zs[128 * 8];        // [d][k], stride 8 (16B-aligned b128 reads)
    __shared__ float s_acc[2][8][128];     // [half][k][j] partial sums
    __shared__ float4 sh4[4];
    int b = blockIdx.x;
    int t = (b & 7) + ((b >> 7) << 3);
    int i0 = ((b >> 3) & 15) * 8;
    int tid = threadIdx.x;
    int j = tid & 127, h = tid >> 7;

    // stage z_sample rows i0..i0+7 for this t: thread (j,h) loads k = h*4..h*4+3 at d=j
#pragma unroll
    for (int kk = 0; kk < 4; ++kk) {
        int k = h * 4 + kk;
        s_zs[j * 8 + k] = zs[(i0 + k) * 4096 + t * 128 + j];   // coalesced
    }
    __syncthreads();

    const float2* zp = zme + t * 16384 + h * 64 * 128;
    float acc[8] = {0.f, 0.f, 0.f, 0.f, 0.f, 0.f, 0.f, 0.f};
#pragma unroll 8
    for (int dd = 0; dd < 64; ++dd) {
        float2 me = zp[dd * 128 + j];                  // coalesced 8B/lane, L2-local
        int d = (h << 6) + dd;
        float4 za = *(const float4*)&s_zs[d * 8];      // LDS broadcast
        float4 zb = *(const float4*)&s_zs[d * 8 + 4];
        float t0;
        t0 = za.x - me.x; acc[0] = fmaf(t0 * t0, me.y, acc[0]);
        t0 = za.y - me.x; acc[1] = fmaf(t0 * t0, me.y, acc[1]);
        t0 = za.z - me.x; acc[2] = fmaf(t0 * t0, me.y, acc[2]);
        t0 = za.w - me.x; acc[3] = fmaf(t0 * t0, me.y, acc[3]);
        t0 = zb.x - me.x; acc[4] = fmaf(t0 * t0, me.y, acc[4]);
        t0 = zb.y - me.x; acc[5] = fmaf(t0 * t0, me.y, acc[5]);
        t0 = zb.z - me.x; acc[6] = fmaf(t0 * t0, me.y, acc[6]);
        t0 = zb.w - me.x; acc[7] = fmaf(t0 * t0, me.y, acc[7]);
    }
#pragma unroll
    for (int k = 0; k < 8; ++k) s_acc[h][k][j] = acc[k];
    __syncthreads();

    // half h finalizes i-rows k0 = h*4 .. h*4+3
    int k0 = h * 4;
    float base = -0.5f * (cz[t * 128 + j] + 128.f * LOG2PI);
    float4 rz, fz;
    rz.x = -0.5f * (s_acc[0][k0 + 0][j] + s_acc[1][k0 + 0][j]) + base;
    rz.y = -0.5f * (s_acc[0][k0 + 1][j] + s_acc[1][k0 + 1][j]) + base;
    rz.z = -0.5f * (s_acc[0][k0 + 2][j] + s_acc[1][k0 + 2][j]) + base;
    rz.w = -0.5f * (s_acc[0][k0 + 3][j] + s_acc[1][k0 + 3][j]) + base;
    fz.x = rz.x + F[(i0 + k0 + 0) * 128 + j];
    fz.y = rz.y + F[(i0 + k0 + 1) * 128 + j];
    fz.z = rz.z + F[(i0 + k0 + 2) * 128 + j];
    fz.w = rz.w + F[(i0 + k0 + 3) * 128 + j];

    float4 mz = halfMax4(rz, sh4);
    float4 e = make_float4(expf(rz.x - mz.x), expf(rz.y - mz.y),
                           expf(rz.z - mz.z), expf(rz.w - mz.w));
    float4 sz = halfSum4(e, sh4);
    float4 mf = halfMax4(fz, sh4);
    e = make_float4(expf(fz.x - mf.x), expf(fz.y - mf.y),
                    expf(fz.z - mf.z), expf(fz.w - mf.w));
    float4 sf = halfSum4(e, sh4);

    if (j == 0) {
        float log_norm = logf(128.f * (float)num_train[0]);
        float lz[4] = {mz.x + logf(sz.x), mz.y + logf(sz.y),
                       mz.z + logf(sz.z), mz.w + logf(sz.w)};
        float lfz[4] = {mf.x + logf(sf.x), mf.y + logf(sf.y),
                        mf.z + logf(sf.z), mf.w + logf(sf.w)};
        float s = 0.f;
#pragma unroll
        for (int k = 0; k < 4; ++k) {
            float v = lfz[k] - lse_f[i0 + k0 + k] - lz[k] + log_norm;
            s += (v > 0.f ? v : 0.f);
        }
        atomicAdd(out, s * (1.f / 4096.f));
    }
}

extern "C" void kernel_launch(void* const* d_in, const int* in_sizes, int n_in,
                              void* d_out, int out_size, void* d_ws, size_t ws_size,
                              hipStream_t stream) {
    const float* f_mean    = (const float*)d_in[0];
    const float* f_logvar  = (const float*)d_in[1];
    const float* f_sample  = (const float*)d_in[2];
    const float* z_mean    = (const float*)d_in[3];
    const float* z_logvar  = (const float*)d_in[4];
    const float* z_sample  = (const float*)d_in[5];
    const int*   num_train = (const int*)d_in[6];
    float* out = (float*)d_out;

    float* ws    = (float*)d_ws;
    float2* zme  = (float2*)ws;              // 524288 float2 (4 MB)
    float2* fme  = (float2*)(ws + 1048576);  // 32768 float2 (256 KB)
    float*  cz   = ws + 1048576 + 65536;     // 4096
    float*  cf   = cz + 4096;                // 128
    float*  F    = cf + 128;                 // 16384
    float*  lse_f= F + 16384;                // 128

    prep<<<NB_TZ + NB_TF + NB_ZS + NB_FS + 1, 256, 0, stream>>>(
        z_mean, z_logvar, f_mean, f_logvar, zme, fme, cz, cf, out);
    fker<<<128, 256, 0, stream>>>(f_sample, fme, cf, F, lse_f);
    zker<<<512, 256, 0, stream>>>(z_sample, zme, cz, F, lse_f, num_train, out);
}